// Round 1
// baseline (138873.743 us; speedup 1.0000x reference)
//
#include <hip/hip_runtime.h>

// LangVisNet on MI355X. Round 1: full-fp32 correctness-first implementation.
// Structure: feedforward phases as small kernels; LSTM scans as persistent
// kernels with LDS-resident weights and a device-scope grid barrier per step.
//
// Key algebraic decomposition (removes ~17 GFLOP of redundant GEMM):
//   q[t,c,hw] = [vis_xy(c) | le[t] | lo[t] | p[t,hw]]  (vis part t-invariant,
//   le/lo parts hw-invariant, p rank-1)  =>
//   pre0[s=(hw,t), g] = A2T[hw][g] + B2[t][g] + p[t,hw]*w2[g]
// where A2T = Wih0 @ (ccW_vis @ vis_xy), B2 = Wih0 @ (Bt rows) + biases,
// w2 = Wih0 @ ccW[:,4690].

#define DEVI __device__ __forceinline__

DEVI float sigm(float x){ return 1.f/(1.f+expf(-x)); }

// ---- device-scope grid barrier (all blocks co-resident by construction) ----
DEVI void gbar(unsigned* cnt, unsigned target){
  __syncthreads();
  if (threadIdx.x == 0){
    __threadfence();
    __hip_atomic_fetch_add(cnt, 1u, __ATOMIC_RELEASE, __HIP_MEMORY_SCOPE_AGENT);
    while (__hip_atomic_load(cnt, __ATOMIC_ACQUIRE, __HIP_MEMORY_SCOPE_AGENT) < target)
      __builtin_amdgcn_s_sleep(2);
    __threadfence();
  }
  __syncthreads();
}

// ---- small kernels ----
__global__ void k_emb(const int* __restrict__ lang, const float* __restrict__ emb,
                      float* __restrict__ le){
  int t = blockIdx.x;
  size_t row = (size_t)lang[t]*1000;
  for (int e = threadIdx.x; e < 1000; e += 256)
    le[t*1000+e] = emb[row+e];
}

__global__ void k_concat(const float* __restrict__ le, const float* __restrict__ lo,
                         float* __restrict__ xc){
  int t = blockIdx.x;
  for (int j = threadIdx.x; j < 2000; j += 256)
    xc[t*2000+j] = (j < 1000) ? le[t*1000+j] : lo[t*1000 + (j-1000)];
}

__global__ void k_wl(const float* __restrict__ ccW, float* __restrict__ row8){
  int m = blockIdx.x*256 + threadIdx.x;
  if (m < 1000) row8[m] = ccW[(size_t)m*4691 + 4690];
}

// out[t][g] = sum_e X[t][e]*W[g][e] (+b1[g]+b2[g] for t<biasTmax), optional sigmoid.
// One block per g.
template<int T>
__global__ void k_rowdot(const float* __restrict__ X, int K,
                         const float* __restrict__ W, int wstride,
                         const float* __restrict__ b1, int b1scalar,
                         const float* __restrict__ b2,
                         int biasTmax, int act,
                         float* __restrict__ out, int ostride){
  int g = blockIdx.x;
  const float* wr = W + (size_t)g*wstride;
  float acc[T];
  #pragma unroll
  for (int t=0;t<T;t++) acc[t]=0.f;
  for (int e = threadIdx.x; e < K; e += 256){
    float wv = wr[e];
    #pragma unroll
    for (int t=0;t<T;t++) acc[t] += X[(size_t)t*K+e]*wv;
  }
  __shared__ float red[T][256];
  #pragma unroll
  for (int t=0;t<T;t++) red[t][threadIdx.x]=acc[t];
  __syncthreads();
  for (int off=128; off>0; off>>=1){
    if (threadIdx.x < off){
      #pragma unroll
      for (int t=0;t<T;t++) red[t][threadIdx.x] += red[t][threadIdx.x+off];
    }
    __syncthreads();
  }
  if (threadIdx.x < T){
    float v = red[threadIdx.x][0];
    if (threadIdx.x < biasTmax){
      if (b1) v += b1scalar ? b1[0] : b1[g];
      if (b2) v += b2[g];
    }
    if (act == 1) v = sigm(v);
    out[(size_t)threadIdx.x*ostride + g] = v;
  }
}

// out[g][hw] (strides og,ohw) = sum_e W[g][e]*X[e][hw]; 4 g-rows per block,
// thread = hw in [0,256). tail=1 appends analytic xgrid/ygrid channels at K,K+1.
__global__ void k_colgemm(const float* __restrict__ W, int wstride, int K,
                          const float* __restrict__ X,
                          float* __restrict__ out, int og, int ohw,
                          int G, int tail){
  __shared__ float wl[4][2688];
  int g0 = blockIdx.x*4;
  for (int i = threadIdx.x; i < 4*K; i += 256){
    int j = i / K, e = i - j*K;
    wl[j][e] = (g0+j < G) ? W[(size_t)(g0+j)*wstride + e] : 0.f;
  }
  __syncthreads();
  int hw = threadIdx.x;
  float a0=0.f,a1=0.f,a2=0.f,a3=0.f;
  #pragma unroll 4
  for (int e = 0; e < K; ++e){
    float xv = X[(size_t)e*256 + hw];
    a0 += wl[0][e]*xv; a1 += wl[1][e]*xv;
    a2 += wl[2][e]*xv; a3 += wl[3][e]*xv;
  }
  if (tail){
    float xsv = -1.f + (2.f/15.f)*(float)(hw & 15);
    float ysv = -1.f + (2.f/15.f)*(float)(hw >> 4);
    a0 += W[(size_t)(g0+0)*wstride + K]*xsv + W[(size_t)(g0+0)*wstride + K+1]*ysv;
    a1 += W[(size_t)(g0+1)*wstride + K]*xsv + W[(size_t)(g0+1)*wstride + K+1]*ysv;
    a2 += W[(size_t)(g0+2)*wstride + K]*xsv + W[(size_t)(g0+2)*wstride + K+1]*ysv;
    a3 += W[(size_t)(g0+3)*wstride + K]*xsv + W[(size_t)(g0+3)*wstride + K+1]*ysv;
  }
  float av[4] = {a0,a1,a2,a3};
  #pragma unroll
  for (int j=0;j<4;j++)
    if (g0+j < G) out[(size_t)(g0+j)*og + (size_t)hw*ohw] = av[j];
}

// p[t][hw] = sum_c filt[t][c]*vis_xy[c][hw]; block per hw.
__global__ void k_p(const float* __restrict__ filt, const float* __restrict__ vis,
                    float* __restrict__ p){
  int hw = blockIdx.x;
  float acc[8];
  #pragma unroll
  for (int t=0;t<8;t++) acc[t]=0.f;
  for (int ch = threadIdx.x; ch < 2688; ch += 256){
    float v = vis[(size_t)ch*256 + hw];
    #pragma unroll
    for (int t=0;t<8;t++) acc[t] += filt[t*2690+ch]*v;
  }
  __shared__ float red[8][256];
  #pragma unroll
  for (int t=0;t<8;t++) red[t][threadIdx.x]=acc[t];
  __syncthreads();
  for (int off=128; off>0; off>>=1){
    if (threadIdx.x < off){
      #pragma unroll
      for (int t=0;t<8;t++) red[t][threadIdx.x]+=red[t][threadIdx.x+off];
    }
    __syncthreads();
  }
  if (threadIdx.x < 8){
    int t = threadIdx.x;
    float xsv = -1.f + (2.f/15.f)*(float)(hw & 15);
    float ysv = -1.f + (2.f/15.f)*(float)(hw >> 4);
    p[t*256+hw] = red[t][0] + filt[t*2690+2688]*xsv + filt[t*2690+2689]*ysv;
  }
}

// ---- persistent LSTM scan ----
// MODE 0 (PRE):      gates = Whh.h + pre[s][g]                       (lang layers)
// MODE 1 (ASSEMBLE): gates = Whh.h + A2T[hw][g]+B2[t][g]+p[t,hw]w2   (mrnn layer0)
// MODE 2 (FUSED):    gates = Whh.h + Wih.x_seq[s] + bih+bhh          (mrnn layers 1,2)
// 4 h-units per block (wave w owns unit blockIdx*4+w); weights fp32 in LDS.
template<int MODE>
__global__ __launch_bounds__(256) void k_scan(
    const float* __restrict__ Whh, const float* __restrict__ Wih,
    const float* __restrict__ pre,
    const float* __restrict__ A2T, const float* __restrict__ B2w,
    const float* __restrict__ pv,
    const float* __restrict__ bih, const float* __restrict__ bhh,
    const float* __restrict__ xseq,
    float* __restrict__ hseq, float* __restrict__ hcur,
    int H, int S, unsigned* __restrict__ cnt)
{
  constexpr int NMAT = (MODE==2) ? 2 : 1;
  __shared__ float wt[NMAT][16][1024];
  __shared__ float hx[NMAT][1024];
  const int tid = threadIdx.x;
  const int w = tid >> 6, lane = tid & 63;
  const int u = blockIdx.x*4 + w;
  const unsigned nb = gridDim.x;

  // load this block's 16 (or 32) weight rows into LDS, zero-padded to 1024
  for (int i = tid; i < NMAT*16*1024; i += 256){
    int m = i >> 14;
    int r = (i >> 10) & 15;
    int e = i & 1023;
    int uu = blockIdx.x*4 + (r >> 2);
    int q = r & 3;
    float v = 0.f;
    if (uu < H && e < H){
      const float* Wm = (m == 0) ? Whh : Wih;
      v = Wm[(size_t)(q*H + uu)*H + e];
    }
    wt[m][r][e] = v;
  }

  float bs0=0.f, bs1=0.f, bs2=0.f, bs3=0.f;
  if (MODE == 2 && u < H){
    bs0 = bih[0*H+u] + bhh[0*H+u];
    bs1 = bih[1*H+u] + bhh[1*H+u];
    bs2 = bih[2*H+u] + bhh[2*H+u];
    bs3 = bih[3*H+u] + bhh[3*H+u];
  }

  float c = 0.f;
  __syncthreads();

  for (int s = 0; s < S; ++s){
    // stage h_prev (and x for FUSED) into LDS
    for (int i = tid; i < 1024; i += 256){
      hx[0][i] = (i < H) ? hcur[i] : 0.f;
      if constexpr (MODE == 2)
        hx[1][i] = (i < H) ? xseq[(size_t)s*H + i] : 0.f;
    }
    __syncthreads();

    if (u < H){
      float a0=0.f,a1=0.f,a2=0.f,a3=0.f;
      float b0=0.f,b1=0.f,b2=0.f,b3=0.f;
      #pragma unroll 4
      for (int k = 0; k < 16; ++k){
        int e = k*64 + lane;
        float h0 = hx[0][e];
        a0 += wt[0][w*4+0][e]*h0;
        a1 += wt[0][w*4+1][e]*h0;
        a2 += wt[0][w*4+2][e]*h0;
        a3 += wt[0][w*4+3][e]*h0;
        if constexpr (MODE == 2){
          float x0 = hx[1][e];
          b0 += wt[1][w*4+0][e]*x0;
          b1 += wt[1][w*4+1][e]*x0;
          b2 += wt[1][w*4+2][e]*x0;
          b3 += wt[1][w*4+3][e]*x0;
        }
      }
      #pragma unroll
      for (int d = 1; d < 64; d <<= 1){
        a0 += __shfl_xor(a0,d,64); a1 += __shfl_xor(a1,d,64);
        a2 += __shfl_xor(a2,d,64); a3 += __shfl_xor(a3,d,64);
        if constexpr (MODE == 2){
          b0 += __shfl_xor(b0,d,64); b1 += __shfl_xor(b1,d,64);
          b2 += __shfl_xor(b2,d,64); b3 += __shfl_xor(b3,d,64);
        }
      }
      float g0,g1,g2,g3;
      if constexpr (MODE == 0){
        size_t base = (size_t)s*4*H + u;
        g0 = a0 + pre[base + 0*(size_t)H];
        g1 = a1 + pre[base + 1*(size_t)H];
        g2 = a2 + pre[base + 2*(size_t)H];
        g3 = a3 + pre[base + 3*(size_t)H];
      } else if constexpr (MODE == 1){
        int hwv = s >> 3, tt = s & 7;
        float pval = pv[tt*256 + hwv];
        size_t ab = (size_t)hwv*4020 + u;
        size_t bb = (size_t)tt*4020 + u;
        g0 = a0 + A2T[ab+0*H] + B2w[bb+0*H] + pval*B2w[8*4020 + 0*H + u];
        g1 = a1 + A2T[ab+1*H] + B2w[bb+1*H] + pval*B2w[8*4020 + 1*H + u];
        g2 = a2 + A2T[ab+2*H] + B2w[bb+2*H] + pval*B2w[8*4020 + 2*H + u];
        g3 = a3 + A2T[ab+3*H] + B2w[bb+3*H] + pval*B2w[8*4020 + 3*H + u];
      } else {
        g0 = a0 + b0 + bs0; g1 = a1 + b1 + bs1;
        g2 = a2 + b2 + bs2; g3 = a3 + b3 + bs3;
      }
      float iv = sigm(g0), fv = sigm(g1), gv = tanhf(g2), ov = sigm(g3);
      c = fv*c + iv*gv;
      float hv = ov*tanhf(c);
      if (lane == 0){
        hcur[u] = hv;
        hseq[(size_t)s*H + u] = hv;
      }
    }
    gbar(cnt, (unsigned)(s+1)*nb);
  }
}

extern "C" void kernel_launch(void* const* d_in, const int* in_sizes, int n_in,
                              void* d_out, int out_size, void* d_ws, size_t ws_size,
                              hipStream_t stream){
  const float* vis   = (const float*)d_in[0];   // (1,2688,16,16)
  const int*   lang  = (const int*)  d_in[1];   // (1,8)
  const float* emb   = (const float*)d_in[2];   // (10000,1000)
  const float* lWih  = (const float*)d_in[3];   // (2,4000,1000)
  const float* lWhh  = (const float*)d_in[4];   // (2,4000,1000)
  const float* lbih  = (const float*)d_in[5];   // (2,4000)
  const float* lbhh  = (const float*)d_in[6];   // (2,4000)
  const float* mWih0 = (const float*)d_in[7];   // (4020,1000)
  const float* mWihR = (const float*)d_in[8];   // (2,4020,1005)
  const float* mWhh  = (const float*)d_in[9];   // (3,4020,1005)
  const float* mbih  = (const float*)d_in[10];  // (3,4020)
  const float* mbhh  = (const float*)d_in[11];  // (3,4020)
  const float* afW   = (const float*)d_in[12];  // (2690,1000)
  const float* afb   = (const float*)d_in[13];  // (2690,)
  const float* ccW   = (const float*)d_in[14];  // (1000,4691)
  const float* ccb   = (const float*)d_in[15];  // (1000,)
  const float* ocW   = (const float*)d_in[16];  // (1,1005)
  const float* ocb   = (const float*)d_in[17];  // (1,)
  float* out = (float*)d_out;                   // (1,1,16,16) fp32
  (void)in_sizes; (void)n_in; (void)out_size; (void)ws_size;

  char* wsb = (char*)d_ws;
  size_t off = 0;
  auto alloc = [&](size_t n)->char*{
    char* r = wsb + off; off = (off + n + 255) & ~(size_t)255; return r;
  };
  unsigned* bar = (unsigned*)alloc(5*256);               // 5 barrier slots
  float* hcur   = (float*)  alloc(5*1024*sizeof(float)); // 5 h-state slots
  size_t zbytes = off;                                   // zeroed each launch
  float* le   = (float*)alloc(8*1000*4);
  float* hl0  = (float*)alloc(8*1000*4);
  float* hl1  = (float*)alloc(8*1000*4);
  float* prel = (float*)alloc(8*4000*4);
  float* filt = (float*)alloc(8*2690*4);
  float* pbuf = (float*)alloc(8*256*4);
  float* Abuf = (float*)alloc((size_t)1000*256*4);
  float* Bt9  = (float*)alloc(9*1000*4);
  float* B2w  = (float*)alloc(9*4020*4);
  float* A2T  = (float*)alloc((size_t)256*4020*4);
  float* Xcat = (float*)alloc(8*2000*4);
  float* h0s  = (float*)alloc((size_t)2048*1005*4);
  float* h1s  = (float*)alloc((size_t)2048*1005*4);
  float* h2s  = (float*)alloc((size_t)2048*1005*4);

  unsigned* bar0 = (unsigned*)((char*)bar + 0*256);
  unsigned* bar1 = (unsigned*)((char*)bar + 1*256);
  unsigned* bar2 = (unsigned*)((char*)bar + 2*256);
  unsigned* bar3 = (unsigned*)((char*)bar + 3*256);
  unsigned* bar4 = (unsigned*)((char*)bar + 4*256);

  (void)hipMemsetAsync(d_ws, 0, zbytes, stream);

  // language path
  k_emb<<<8,256,0,stream>>>(lang, emb, le);
  k_rowdot<8><<<4000,256,0,stream>>>(le, 1000, lWih, 1000, lbih, 0, lbhh, 8, 0, prel, 4000);
  k_scan<0><<<250,256,0,stream>>>(lWhh, nullptr, prel, nullptr,nullptr,nullptr,
                                  nullptr,nullptr,nullptr, hl0, hcur+0*1024, 1000, 8, bar0);
  k_rowdot<8><<<4000,256,0,stream>>>(hl0, 1000, lWih+(size_t)4000*1000, 1000,
                                     lbih+4000, 0, lbhh+4000, 8, 0, prel, 4000);
  k_scan<0><<<250,256,0,stream>>>(lWhh+(size_t)4000*1000, nullptr, prel,
                                  nullptr,nullptr,nullptr, nullptr,nullptr,nullptr,
                                  hl1, hcur+1*1024, 1000, 8, bar1);
  // attention filter + p
  k_rowdot<8><<<2690,256,0,stream>>>(hl1, 1000, afW, 1000, afb, 0, nullptr, 8, 1, filt, 2690);
  k_p<<<256,256,0,stream>>>(filt, vis, pbuf);
  // cc decomposition: A, Bt(+ccb), wl, then B2w (+mrnn biases) and A2T
  k_colgemm<<<250,256,0,stream>>>(ccW, 4691, 2688, vis, Abuf, 256, 1, 1000, 1);
  k_concat<<<8,256,0,stream>>>(le, hl1, Xcat);
  k_rowdot<8><<<1000,256,0,stream>>>(Xcat, 2000, ccW+2690, 4691, ccb, 0, nullptr, 8, 0, Bt9, 1000);
  k_wl<<<4,256,0,stream>>>(ccW, Bt9+8*1000);
  k_rowdot<9><<<4020,256,0,stream>>>(Bt9, 1000, mWih0, 1000, mbih, 0, mbhh, 8, 0, B2w, 4020);
  k_colgemm<<<1005,256,0,stream>>>(mWih0, 1000, 1000, Abuf, A2T, 1, 4020, 4020, 0);
  // mRNN: 3 sequential scans over S=2048
  k_scan<1><<<252,256,0,stream>>>(mWhh, nullptr, nullptr, A2T, B2w, pbuf,
                                  nullptr,nullptr,nullptr, h0s, hcur+2*1024, 1005, 2048, bar2);
  k_scan<2><<<252,256,0,stream>>>(mWhh+(size_t)1*4020*1005, mWihR, nullptr,
                                  nullptr,nullptr,nullptr, mbih+4020, mbhh+4020,
                                  h0s, h1s, hcur+3*1024, 1005, 2048, bar3);
  k_scan<2><<<252,256,0,stream>>>(mWhh+(size_t)2*4020*1005, mWihR+(size_t)4020*1005, nullptr,
                                  nullptr,nullptr,nullptr, mbih+2*4020, mbhh+2*4020,
                                  h1s, h2s, hcur+4*1024, 1005, 2048, bar4);
  // output head: out[hw'] = oc_W . h2[1792+hw'] + oc_b
  k_rowdot<1><<<256,256,0,stream>>>(ocW, 1005, h2s+(size_t)1792*1005, 1005,
                                    ocb, 1, nullptr, 1, 0, out, 256);
}

// Round 2
// 16819.315 us; speedup vs baseline: 8.2568x; 8.2568x over previous
//
#include <hip/hip_runtime.h>

// LangVisNet on MI355X. Round 2: fence-free tagged-handshake LSTM scans with
// register-resident weights.
//
// Decomposition (unchanged from round 1, validated):
//   pre0[s=(hw,t), g] = A2T[hw][g] + B2[t][g] + p[t,hw]*w2[g]
//
// Scan sync: h values published as 8-byte {tag=step+1, f32 bits} relaxed
// agent-scope atomics (sc1 -> coherent at MALL), double-buffered by parity.
// Consumers spin per-element on the tag. No fences, no RMW barrier.

#define DEVI __device__ __forceinline__

DEVI float sigm(float x){ return 1.f/(1.f+expf(-x)); }

// ---- small kernels (validated in round 1) ----
__global__ void k_emb(const int* __restrict__ lang, const float* __restrict__ emb,
                      float* __restrict__ le){
  int t = blockIdx.x;
  size_t row = (size_t)lang[t]*1000;
  for (int e = threadIdx.x; e < 1000; e += 256)
    le[t*1000+e] = emb[row+e];
}

__global__ void k_concat(const float* __restrict__ le, const float* __restrict__ lo,
                         float* __restrict__ xc){
  int t = blockIdx.x;
  for (int j = threadIdx.x; j < 2000; j += 256)
    xc[t*2000+j] = (j < 1000) ? le[t*1000+j] : lo[t*1000 + (j-1000)];
}

__global__ void k_wl(const float* __restrict__ ccW, float* __restrict__ row8){
  int m = blockIdx.x*256 + threadIdx.x;
  if (m < 1000) row8[m] = ccW[(size_t)m*4691 + 4690];
}

template<int T>
__global__ void k_rowdot(const float* __restrict__ X, int K,
                         const float* __restrict__ W, int wstride,
                         const float* __restrict__ b1, int b1scalar,
                         const float* __restrict__ b2,
                         int biasTmax, int act,
                         float* __restrict__ out, int ostride){
  int g = blockIdx.x;
  const float* wr = W + (size_t)g*wstride;
  float acc[T];
  #pragma unroll
  for (int t=0;t<T;t++) acc[t]=0.f;
  for (int e = threadIdx.x; e < K; e += 256){
    float wv = wr[e];
    #pragma unroll
    for (int t=0;t<T;t++) acc[t] += X[(size_t)t*K+e]*wv;
  }
  __shared__ float red[T][256];
  #pragma unroll
  for (int t=0;t<T;t++) red[t][threadIdx.x]=acc[t];
  __syncthreads();
  for (int off=128; off>0; off>>=1){
    if (threadIdx.x < off){
      #pragma unroll
      for (int t=0;t<T;t++) red[t][threadIdx.x] += red[t][threadIdx.x+off];
    }
    __syncthreads();
  }
  if (threadIdx.x < T){
    float v = red[threadIdx.x][0];
    if (threadIdx.x < biasTmax){
      if (b1) v += b1scalar ? b1[0] : b1[g];
      if (b2) v += b2[g];
    }
    if (act == 1) v = sigm(v);
    out[(size_t)threadIdx.x*ostride + g] = v;
  }
}

__global__ void k_colgemm(const float* __restrict__ W, int wstride, int K,
                          const float* __restrict__ X,
                          float* __restrict__ out, int og, int ohw,
                          int G, int tail){
  __shared__ float wl[4][2688];
  int g0 = blockIdx.x*4;
  for (int i = threadIdx.x; i < 4*K; i += 256){
    int j = i / K, e = i - j*K;
    wl[j][e] = (g0+j < G) ? W[(size_t)(g0+j)*wstride + e] : 0.f;
  }
  __syncthreads();
  int hw = threadIdx.x;
  float a0=0.f,a1=0.f,a2=0.f,a3=0.f;
  #pragma unroll 4
  for (int e = 0; e < K; ++e){
    float xv = X[(size_t)e*256 + hw];
    a0 += wl[0][e]*xv; a1 += wl[1][e]*xv;
    a2 += wl[2][e]*xv; a3 += wl[3][e]*xv;
  }
  if (tail){
    float xsv = -1.f + (2.f/15.f)*(float)(hw & 15);
    float ysv = -1.f + (2.f/15.f)*(float)(hw >> 4);
    a0 += W[(size_t)(g0+0)*wstride + K]*xsv + W[(size_t)(g0+0)*wstride + K+1]*ysv;
    a1 += W[(size_t)(g0+1)*wstride + K]*xsv + W[(size_t)(g0+1)*wstride + K+1]*ysv;
    a2 += W[(size_t)(g0+2)*wstride + K]*xsv + W[(size_t)(g0+2)*wstride + K+1]*ysv;
    a3 += W[(size_t)(g0+3)*wstride + K]*xsv + W[(size_t)(g0+3)*wstride + K+1]*ysv;
  }
  float av[4] = {a0,a1,a2,a3};
  #pragma unroll
  for (int j=0;j<4;j++)
    if (g0+j < G) out[(size_t)(g0+j)*og + (size_t)hw*ohw] = av[j];
}

__global__ void k_p(const float* __restrict__ filt, const float* __restrict__ vis,
                    float* __restrict__ p){
  int hw = blockIdx.x;
  float acc[8];
  #pragma unroll
  for (int t=0;t<8;t++) acc[t]=0.f;
  for (int ch = threadIdx.x; ch < 2688; ch += 256){
    float v = vis[(size_t)ch*256 + hw];
    #pragma unroll
    for (int t=0;t<8;t++) acc[t] += filt[t*2690+ch]*v;
  }
  __shared__ float red[8][256];
  #pragma unroll
  for (int t=0;t<8;t++) red[t][threadIdx.x]=acc[t];
  __syncthreads();
  for (int off=128; off>0; off>>=1){
    if (threadIdx.x < off){
      #pragma unroll
      for (int t=0;t<8;t++) red[t][threadIdx.x]+=red[t][threadIdx.x+off];
    }
    __syncthreads();
  }
  if (threadIdx.x < 8){
    int t = threadIdx.x;
    float xsv = -1.f + (2.f/15.f)*(float)(hw & 15);
    float ysv = -1.f + (2.f/15.f)*(float)(hw >> 4);
    p[t*256+hw] = red[t][0] + filt[t*2690+2688]*xsv + filt[t*2690+2689]*ysv;
  }
}

// ---- persistent LSTM scan, tagged-handshake, register weights ----
// MODE 0: gates = Whh.h + pre[s][g]                 (lang layers; pre has biases)
// MODE 1: gates = Whh.h + A2T[hw]+B2[t]+p*w2        (mrnn layer 0)
// MODE 2: gates = Whh.h + Wih.x[s] + bih+bhh        (mrnn layers 1,2)
// Block = 512 threads = 8 waves; wave w owns unit u = bid*8+w.
// Lane k-stripe: e = lane*4 + jj + 256*j2, j2=0..3, jj=0..3 (16 elems/lane).
template<int MODE, int H>
__global__ __launch_bounds__(512, 2) void k_scan(
    const float* __restrict__ Whh, const float* __restrict__ Wih,
    const float* __restrict__ pre,
    const float* __restrict__ A2T, const float* __restrict__ B2w,
    const float* __restrict__ pv,
    const float* __restrict__ bih, const float* __restrict__ bhh,
    const float* __restrict__ xseq,
    float* __restrict__ hseq, unsigned long long* __restrict__ hctag,
    int S)
{
  constexpr int NREG = (MODE==2) ? 8 : 4;
  __shared__ float hx[(MODE==2) ? 2048 : 1024];
  float* xx = (MODE==2) ? (hx + 1024) : hx;   // alias unused in MODE!=2

  const int tid  = threadIdx.x;
  const int w    = tid >> 6;
  const int lane = tid & 63;
  const int u    = blockIdx.x*8 + w;
  const int uu   = (u < H) ? u : H-1;

  // ---- load weights into registers (one-time) ----
  float wreg[NREG][16];
  #pragma unroll
  for (int r = 0; r < NREG; ++r){
    const int q = r & 3;
    const float* base = (r < 4) ? Whh : Wih;
    const float* row = base + (size_t)(q*H + uu)*H;
    #pragma unroll
    for (int j2 = 0; j2 < 4; ++j2){
      #pragma unroll
      for (int jj = 0; jj < 4; ++jj){
        const int e = (lane<<2) + jj + (j2<<8);
        wreg[r][j2*4+jj] = (u < H && e < H) ? row[e] : 0.f;
      }
    }
  }

  float bs0=0.f, bs1=0.f, bs2=0.f, bs3=0.f;
  if constexpr (MODE == 2){
    bs0 = bih[0*H+uu] + bhh[0*H+uu];
    bs1 = bih[1*H+uu] + bhh[1*H+uu];
    bs2 = bih[2*H+uu] + bhh[2*H+uu];
    bs3 = bih[3*H+uu] + bhh[3*H+uu];
  }

  // zero LDS pads once
  for (int i = tid; i < 1024; i += 512){
    if (i >= H){ hx[i] = 0.f; if constexpr (MODE==2) xx[i] = 0.f; }
  }

  float cst = 0.f;

  for (int s = 0; s < S; ++s){
    // stage x (plain cached loads; producer kernel ended -> visible)
    if constexpr (MODE == 2){
      for (int i = tid; i < H; i += 512)
        xx[i] = xseq[(size_t)s*H + i];
    }
    // spin-stage h(s-1): slot (s-1)&1 == (s+1)&1, want tag >= s
    {
      unsigned long long* src = hctag + (((unsigned)(s+1) & 1u) << 10);
      for (int i = tid; i < H; i += 512){
        unsigned long long v =
          __hip_atomic_load(&src[i], __ATOMIC_RELAXED, __HIP_MEMORY_SCOPE_AGENT);
        int it = 0;
        while ((unsigned)(v >> 32) < (unsigned)s){
          __builtin_amdgcn_s_sleep(1);
          ++it;
          v = (it < 16384)
            ? __hip_atomic_load(&src[i], __ATOMIC_RELAXED, __HIP_MEMORY_SCOPE_AGENT)
            : __hip_atomic_load(&src[i], __ATOMIC_ACQUIRE, __HIP_MEMORY_SCOPE_AGENT);
        }
        hx[i] = __uint_as_float((unsigned)v);
      }
    }
    __syncthreads();

    // per-step gate extras (issued early; overlap with FMA loop)
    float e0, e1, e2, e3;
    if constexpr (MODE == 0){
      const size_t base = (size_t)s*4*H + uu;
      e0 = pre[base + 0*(size_t)H]; e1 = pre[base + 1*(size_t)H];
      e2 = pre[base + 2*(size_t)H]; e3 = pre[base + 3*(size_t)H];
    } else if constexpr (MODE == 1){
      const int hwv = s >> 3, tt = s & 7;
      const float pval = pv[tt*256 + hwv];
      const size_t ab = (size_t)hwv*4020 + uu;
      const size_t bb = (size_t)tt*4020 + uu;
      e0 = A2T[ab+0*H] + B2w[bb+0*H] + pval*B2w[8*4020 + 0*H + uu];
      e1 = A2T[ab+1*H] + B2w[bb+1*H] + pval*B2w[8*4020 + 1*H + uu];
      e2 = A2T[ab+2*H] + B2w[bb+2*H] + pval*B2w[8*4020 + 2*H + uu];
      e3 = A2T[ab+3*H] + B2w[bb+3*H] + pval*B2w[8*4020 + 3*H + uu];
    } else {
      e0 = bs0; e1 = bs1; e2 = bs2; e3 = bs3;
    }

    // matvec: acc[q] = Whh_q . h (+ Wih_q . x)
    float a0=0.f, a1=0.f, a2=0.f, a3=0.f;
    #pragma unroll
    for (int j2 = 0; j2 < 4; ++j2){
      const float4 hv = *reinterpret_cast<const float4*>(&hx[(lane<<2) + (j2<<8)]);
      a0 += wreg[0][j2*4+0]*hv.x + wreg[0][j2*4+1]*hv.y
          + wreg[0][j2*4+2]*hv.z + wreg[0][j2*4+3]*hv.w;
      a1 += wreg[1][j2*4+0]*hv.x + wreg[1][j2*4+1]*hv.y
          + wreg[1][j2*4+2]*hv.z + wreg[1][j2*4+3]*hv.w;
      a2 += wreg[2][j2*4+0]*hv.x + wreg[2][j2*4+1]*hv.y
          + wreg[2][j2*4+2]*hv.z + wreg[2][j2*4+3]*hv.w;
      a3 += wreg[3][j2*4+0]*hv.x + wreg[3][j2*4+1]*hv.y
          + wreg[3][j2*4+2]*hv.z + wreg[3][j2*4+3]*hv.w;
      if constexpr (MODE == 2){
        const float4 xv = *reinterpret_cast<const float4*>(&xx[(lane<<2) + (j2<<8)]);
        a0 += wreg[4][j2*4+0]*xv.x + wreg[4][j2*4+1]*xv.y
            + wreg[4][j2*4+2]*xv.z + wreg[4][j2*4+3]*xv.w;
        a1 += wreg[5][j2*4+0]*xv.x + wreg[5][j2*4+1]*xv.y
            + wreg[5][j2*4+2]*xv.z + wreg[5][j2*4+3]*xv.w;
        a2 += wreg[6][j2*4+0]*xv.x + wreg[6][j2*4+1]*xv.y
            + wreg[6][j2*4+2]*xv.z + wreg[6][j2*4+3]*xv.w;
        a3 += wreg[7][j2*4+0]*xv.x + wreg[7][j2*4+1]*xv.y
            + wreg[7][j2*4+2]*xv.z + wreg[7][j2*4+3]*xv.w;
      }
    }
    // butterfly reduce (all lanes end with full sums)
    #pragma unroll
    for (int d = 1; d < 64; d <<= 1){
      a0 += __shfl_xor(a0, d, 64); a1 += __shfl_xor(a1, d, 64);
      a2 += __shfl_xor(a2, d, 64); a3 += __shfl_xor(a3, d, 64);
    }

    const float iv = sigm(a0 + e0);
    const float fv = sigm(a1 + e1);
    const float gv = tanhf(a2 + e2);
    const float ov = sigm(a3 + e3);
    cst = fv*cst + iv*gv;
    const float hv = ov*tanhf(cst);

    if (lane == 0 && u < H){
      const unsigned long long pk =
        ((unsigned long long)(unsigned)(s+1) << 32) | (unsigned)__float_as_uint(hv);
      __hip_atomic_store(&hctag[((unsigned)s & 1u)*1024 + u], pk,
                         __ATOMIC_RELAXED, __HIP_MEMORY_SCOPE_AGENT);
      hseq[(size_t)s*H + u] = hv;
    }
    __syncthreads();   // protect hx/xx from next step's staging
  }
}

extern "C" void kernel_launch(void* const* d_in, const int* in_sizes, int n_in,
                              void* d_out, int out_size, void* d_ws, size_t ws_size,
                              hipStream_t stream){
  const float* vis   = (const float*)d_in[0];
  const int*   lang  = (const int*)  d_in[1];
  const float* emb   = (const float*)d_in[2];
  const float* lWih  = (const float*)d_in[3];
  const float* lWhh  = (const float*)d_in[4];
  const float* lbih  = (const float*)d_in[5];
  const float* lbhh  = (const float*)d_in[6];
  const float* mWih0 = (const float*)d_in[7];
  const float* mWihR = (const float*)d_in[8];
  const float* mWhh  = (const float*)d_in[9];
  const float* mbih  = (const float*)d_in[10];
  const float* mbhh  = (const float*)d_in[11];
  const float* afW   = (const float*)d_in[12];
  const float* afb   = (const float*)d_in[13];
  const float* ccW   = (const float*)d_in[14];
  const float* ccb   = (const float*)d_in[15];
  const float* ocW   = (const float*)d_in[16];
  const float* ocb   = (const float*)d_in[17];
  float* out = (float*)d_out;
  (void)in_sizes; (void)n_in; (void)out_size; (void)ws_size;

  char* wsb = (char*)d_ws;
  size_t off = 0;
  auto alloc = [&](size_t n)->char*{
    char* r = wsb + off; off = (off + n + 255) & ~(size_t)255; return r;
  };
  // tagged h double-buffers: 5 scans x 2 slots x 1024 x 8B (zeroed each launch)
  unsigned long long* hct = (unsigned long long*)alloc(5*2*1024*8);
  size_t zbytes = off;
  float* le   = (float*)alloc(8*1000*4);
  float* hl0  = (float*)alloc(8*1000*4);
  float* hl1  = (float*)alloc(8*1000*4);
  float* prel = (float*)alloc(8*4000*4);
  float* filt = (float*)alloc(8*2690*4);
  float* pbuf = (float*)alloc(8*256*4);
  float* Abuf = (float*)alloc((size_t)1000*256*4);
  float* Bt9  = (float*)alloc(9*1000*4);
  float* B2w  = (float*)alloc(9*4020*4);
  float* A2T  = (float*)alloc((size_t)256*4020*4);
  float* Xcat = (float*)alloc(8*2000*4);
  float* h0s  = (float*)alloc((size_t)2048*1005*4);
  float* h1s  = (float*)alloc((size_t)2048*1005*4);
  float* h2s  = (float*)alloc((size_t)2048*1005*4);

  unsigned long long* hct0 = hct + 0*2048;
  unsigned long long* hct1 = hct + 1*2048;
  unsigned long long* hct2 = hct + 2*2048;
  unsigned long long* hct3 = hct + 3*2048;
  unsigned long long* hct4 = hct + 4*2048;

  (void)hipMemsetAsync(d_ws, 0, zbytes, stream);

  // language path
  k_emb<<<8,256,0,stream>>>(lang, emb, le);
  k_rowdot<8><<<4000,256,0,stream>>>(le, 1000, lWih, 1000, lbih, 0, lbhh, 8, 0, prel, 4000);
  k_scan<0,1000><<<125,512,0,stream>>>(lWhh, nullptr, prel,
                                       nullptr,nullptr,nullptr, nullptr,nullptr,nullptr,
                                       hl0, hct0, 8);
  k_rowdot<8><<<4000,256,0,stream>>>(hl0, 1000, lWih+(size_t)4000*1000, 1000,
                                     lbih+4000, 0, lbhh+4000, 8, 0, prel, 4000);
  k_scan<0,1000><<<125,512,0,stream>>>(lWhh+(size_t)4000*1000, nullptr, prel,
                                       nullptr,nullptr,nullptr, nullptr,nullptr,nullptr,
                                       hl1, hct1, 8);
  // attention filter + p
  k_rowdot<8><<<2690,256,0,stream>>>(hl1, 1000, afW, 1000, afb, 0, nullptr, 8, 1, filt, 2690);
  k_p<<<256,256,0,stream>>>(filt, vis, pbuf);
  // cc decomposition
  k_colgemm<<<250,256,0,stream>>>(ccW, 4691, 2688, vis, Abuf, 256, 1, 1000, 1);
  k_concat<<<8,256,0,stream>>>(le, hl1, Xcat);
  k_rowdot<8><<<1000,256,0,stream>>>(Xcat, 2000, ccW+2690, 4691, ccb, 0, nullptr, 8, 0, Bt9, 1000);
  k_wl<<<4,256,0,stream>>>(ccW, Bt9+8*1000);
  k_rowdot<9><<<4020,256,0,stream>>>(Bt9, 1000, mWih0, 1000, mbih, 0, mbhh, 8, 0, B2w, 4020);
  k_colgemm<<<1005,256,0,stream>>>(mWih0, 1000, 1000, Abuf, A2T, 1, 4020, 4020, 0);
  // mRNN: 3 sequential scans over S=2048
  k_scan<1,1005><<<126,512,0,stream>>>(mWhh, nullptr, nullptr,
                                       A2T, B2w, pbuf, nullptr,nullptr,nullptr,
                                       h0s, hct2, 2048);
  k_scan<2,1005><<<126,512,0,stream>>>(mWhh+(size_t)1*4020*1005, mWihR, nullptr,
                                       nullptr,nullptr,nullptr,
                                       mbih+4020, mbhh+4020, h0s,
                                       h1s, hct3, 2048);
  k_scan<2,1005><<<126,512,0,stream>>>(mWhh+(size_t)2*4020*1005, mWihR+(size_t)4020*1005, nullptr,
                                       nullptr,nullptr,nullptr,
                                       mbih+2*4020, mbhh+2*4020, h1s,
                                       h2s, hct4, 2048);
  // output head
  k_rowdot<1><<<256,256,0,stream>>>(ocW, 1005, h2s+(size_t)1792*1005, 1005,
                                    ocb, 1, nullptr, 1, 0, out, 256);
}